// Round 7
// baseline (324.185 us; speedup 1.0000x reference)
//
#include <hip/hip_runtime.h>
#include <math.h>

#define B_    32
#define S_    4096
#define DIN_  256
#define D_    256
#define T_    256
#define NB_   4
#define K_    5
#define EPS_  1e-5f
#define ROWS_ (B_ * T_)   // 8192

#define ORS_  16          // owned rows per block
#define HR_   20          // owned + 2 halo rows each side
#define ASTR  264         // bf16 row stride (528 B, 16B-aligned)

typedef short  shortx8 __attribute__((ext_vector_type(8)));
typedef float  floatx4 __attribute__((ext_vector_type(4)));

__device__ __forceinline__ unsigned short f2bf(float f) {
    unsigned int u = __float_as_uint(f);
    u += 0x7FFFu + ((u >> 16) & 1u);
    return (unsigned short)(u >> 16);
}
__device__ __forceinline__ unsigned int pack2bf(float a, float b) {
    return (unsigned int)f2bf(a) | ((unsigned int)f2bf(b) << 16);
}
__device__ __forceinline__ float bf2f_lo(unsigned int u) {
    return __uint_as_float(u << 16);
}
__device__ __forceinline__ float bf2f_hi(unsigned int u) {
    return __uint_as_float(u & 0xFFFF0000u);
}

// ---------------------------------------------------------------------------
// Setup: weight transpose+convert (z=0..8) and batch lengths (z=9).
// ---------------------------------------------------------------------------
__global__ void k_setup(const float* __restrict__ in_w, const float* __restrict__ win_w,
                        const float* __restrict__ wout_w, const unsigned int* __restrict__ mask_w,
                        unsigned short* __restrict__ wt_in, unsigned short* __restrict__ wt_win,
                        unsigned short* __restrict__ wt_wout, int* __restrict__ lengths) {
    int z = blockIdx.z;
    int tid = threadIdx.x;

    if (z == 9) {
        int b = blockIdx.y * 16 + blockIdx.x;
        if (b >= B_) return;
        int mode = 0;   // mask dtype detection (validated R1-R6)
        unsigned int w0 = mask_w[0];
        if (w0 == 0x3F800000u) mode = 2;
        else {
            bool u8 = false;
            for (int i = 0; i < 32; ++i)
                if (mask_w[i * 1024] > 1u) { u8 = true; break; }
            mode = u8 ? 1 : 0;
        }
        int s = 0;
        if (mode == 0) {
            const int* m = (const int*)mask_w;
            for (int i = tid; i < S_; i += 256) s += (m[(size_t)b * S_ + i] != 0);
        } else if (mode == 2) {
            const float* m = (const float*)mask_w;
            for (int i = tid; i < S_; i += 256) s += (m[(size_t)b * S_ + i] != 0.0f);
        } else {
            const unsigned char* m = (const unsigned char*)mask_w;
            for (int i = tid; i < S_; i += 256) s += (m[(size_t)b * S_ + i] != 0);
        }
        __shared__ int sm[256];
        sm[tid] = s;
        __syncthreads();
        for (int off = 128; off > 0; off >>= 1) {
            if (tid < off) sm[tid] += sm[tid + off];
            __syncthreads();
        }
        if (tid == 0) lengths[b] = sm[0];
        return;
    }

    const float* src; unsigned short* dst; int N, Kd;
    if (z == 0)      { src = in_w;                                   dst = wt_in;                                   N = D_;     Kd = DIN_; }
    else if (z <= 4) { src = win_w  + (size_t)(z - 1) * D_ * 2 * D_; dst = wt_win  + (size_t)(z - 1) * 2 * D_ * D_; N = 2 * D_; Kd = D_; }
    else             { src = wout_w + (size_t)(z - 5) * D_ * D_;     dst = wt_wout + (size_t)(z - 5) * D_ * D_;     N = D_;     Kd = D_; }
    int bx = blockIdx.x * 32;
    int by = blockIdx.y * 32;
    if (bx >= N) return;
    __shared__ float tile[32][33];
    int tx = tid & 31, ty = tid >> 5;
#pragma unroll
    for (int i = 0; i < 32; i += 8)
        tile[ty + i][tx] = src[(size_t)(by + ty + i) * N + bx + tx];
    __syncthreads();
#pragma unroll
    for (int i = 0; i < 32; i += 8)
        dst[(size_t)(bx + ty + i) * Kd + by + tx] = f2bf(tile[tx][ty + i]);
}

// ---------------------------------------------------------------------------
// Front: compress + in-proj -> h0. Grid 512 = 32 b x 16 segs of 16 rows.
// ---------------------------------------------------------------------------
__global__ __launch_bounds__(512, 4) void k_front(
    const float* __restrict__ x, const int* __restrict__ lengths,
    const unsigned short* __restrict__ wt_in, const float* __restrict__ in_b,
    float* __restrict__ h0)
{
    __shared__ unsigned short bufC[ORS_][ASTR];
    int tid = threadIdx.x;
    int w = tid >> 6, lane = tid & 63;
    int c16 = lane & 15, q = lane >> 4;
    int b = blockIdx.x >> 4, seg = blockIdx.x & 15;
    int t0 = seg * ORS_;
    int L = lengths[b];
    {
        int tq = tid & 63, rg = tid >> 6;
        int col = tq * 4;
        float Lf = (float)L;
        float hi = fmaxf(Lf - 1.0f, 0.0f);
        int L1 = max(L - 1, 0);
        const float* xb = x + (size_t)b * S_ * DIN_ + col;
#pragma unroll
        for (int e = 0; e < 2; ++e) {
            int row = rg + e * 8;
            int t = t0 + row;
            float src = ((float)t + 0.5f) * (Lf * (1.0f / T_)) - 0.5f;
            src = fminf(fmaxf(src, 0.0f), hi);
            int i0 = (int)floorf(src);
            int i1 = min(i0 + 1, L1);
            float wf = src - (float)i0;
            float4 v0 = *(const float4*)&xb[(size_t)i0 * DIN_];
            float4 v1 = *(const float4*)&xb[(size_t)i1 * DIN_];
            uint2 o;
            o.x = pack2bf((1.0f - wf) * v0.x + wf * v1.x, (1.0f - wf) * v0.y + wf * v1.y);
            o.y = pack2bf((1.0f - wf) * v0.z + wf * v1.z, (1.0f - wf) * v0.w + wf * v1.w);
            *(uint2*)&bufC[row][col] = o;
        }
    }
    __syncthreads();
#pragma unroll
    for (int nn = 0; nn < 2; ++nn) {
        int nt = w + nn * 8;
        const unsigned short* wp = wt_in + (size_t)(nt * 16 + c16) * 256 + q * 8;
        shortx8 Bf[8];
#pragma unroll
        for (int kk = 0; kk < 8; ++kk) Bf[kk] = *(const shortx8*)(wp + kk * 32);
        floatx4 acc = {};
#pragma unroll
        for (int kk = 0; kk < 8; ++kk) {
            shortx8 a = *(const shortx8*)&bufC[c16][kk * 32 + q * 8];
            acc = __builtin_amdgcn_mfma_f32_16x16x32_bf16(a, Bf[kk], acc, 0, 0, 0);
        }
        float ob = in_b[nt * 16 + c16];
#pragma unroll
        for (int r = 0; r < 4; ++r) {
            int row = q * 4 + r;
            h0[((size_t)b * T_ + t0 + row) * D_ + nt * 16 + c16] = acc[r] + ob;
        }
    }
}

// ---------------------------------------------------------------------------
// One conv block: LN (halo-exact) -> dwconv -> win+act -> wout+residual.
// Grid 512 = 32 b x 16 segs of 16 rows -> 2 blocks/CU co-resident.
// last==1: apply final LN and write out0/out1 instead of hout.
// ---------------------------------------------------------------------------
__global__ __launch_bounds__(512, 4) void k_blk(
    const float* __restrict__ hin, float* __restrict__ hout,
    const float* __restrict__ g_i, const float* __restrict__ b_i,
    const float* __restrict__ dww, const float* __restrict__ dwb,
    const unsigned short* __restrict__ ww, const float* __restrict__ wb,
    const unsigned short* __restrict__ ow, const float* __restrict__ ob,
    const float* __restrict__ fn_g, const float* __restrict__ fn_b,
    float* __restrict__ out0, float* __restrict__ out1, int last)
{
    __shared__ unsigned short buf0[HR_][ASTR];   // 10.6 KB
    __shared__ unsigned short buf1[ORS_][ASTR];  // 8.4 KB
    __shared__ float2 st[ORS_];
    __shared__ float rowS[8][ORS_];
    __shared__ float rowSS[8][ORS_];

    int tid = threadIdx.x;
    int w = tid >> 6, lane = tid & 63;
    int c16 = lane & 15, q = lane >> 4;
    int b = blockIdx.x >> 4, seg = blockIdx.x & 15;
    int t0 = seg * ORS_;

    // ---- Stage A: load h (own+halo) as float4, row stats, LN -> buf0 packed ----
    {
        int c4 = lane * 4;
        float4 g4 = *(const float4*)&g_i[c4];
        float4 b4 = *(const float4*)&b_i[c4];
        float4 vv[3];
#pragma unroll
        for (int it = 0; it < 3; ++it) {
            int r = w + it * 8;
            int t = t0 - 2 + r;
            bool ok = (r < HR_) && (t >= 0) && (t < T_);
            int tc = min(max(t, 0), T_ - 1);
            float4 v = *(const float4*)&hin[((size_t)b * T_ + tc) * D_ + c4];
            vv[it].x = ok ? v.x : 0.0f;
            vv[it].y = ok ? v.y : 0.0f;
            vv[it].z = ok ? v.z : 0.0f;
            vv[it].w = ok ? v.w : 0.0f;
        }
#pragma unroll
        for (int it = 0; it < 3; ++it) {
            int r = w + it * 8;
            if (r < HR_) {
                float s  = vv[it].x + vv[it].y + vv[it].z + vv[it].w;
                float ss = vv[it].x * vv[it].x + vv[it].y * vv[it].y
                         + vv[it].z * vv[it].z + vv[it].w * vv[it].w;
#pragma unroll
                for (int off = 1; off < 64; off <<= 1) {
                    s += __shfl_xor(s, off);
                    ss += __shfl_xor(ss, off);
                }
                float mu = s * (1.0f / D_);
                float rsig = rsqrtf(ss * (1.0f / D_) - mu * mu + EPS_);
                uint2 o;
                o.x = pack2bf((vv[it].x - mu) * rsig * g4.x + b4.x,
                              (vv[it].y - mu) * rsig * g4.y + b4.y);
                o.y = pack2bf((vv[it].z - mu) * rsig * g4.z + b4.z,
                              (vv[it].w - mu) * rsig * g4.w + b4.w);
                int t = t0 - 2 + r;
                if (t < 0 || t >= T_) { o.x = 0; o.y = 0; }
                *(uint2*)&buf0[r][c4] = o;
            }
        }
    }
    // prefetch first win weight tile across the barrier
    shortx8 Bf[8];
    {
        const unsigned short* wp = ww + (size_t)(w * 16 + c16) * 256 + q * 8;
#pragma unroll
        for (int kk = 0; kk < 8; ++kk) Bf[kk] = *(const shortx8*)(wp + kk * 32);
    }
    __syncthreads();

    // ---- Stage B: depthwise conv buf0 -> buf1 (4 cols x 2 rows per thread) ----
    {
        int tq = tid & 63, rg = tid >> 6;
        int col = tq * 4;
        float4 wk[K_];
#pragma unroll
        for (int k = 0; k < K_; ++k) {
            wk[k].x = dww[(col + 0) * K_ + k];
            wk[k].y = dww[(col + 1) * K_ + k];
            wk[k].z = dww[(col + 2) * K_ + k];
            wk[k].w = dww[(col + 3) * K_ + k];
        }
        float4 cb4 = *(const float4*)&dwb[col];
#pragma unroll
        for (int e = 0; e < 2; ++e) {
            int rr = rg + e * 8;
            float4 acc = cb4;
#pragma unroll
            for (int k = 0; k < K_; ++k) {
                uint2 u = *(const uint2*)&buf0[rr + k][col];
                acc.x += bf2f_lo(u.x) * wk[k].x;
                acc.y += bf2f_hi(u.x) * wk[k].y;
                acc.z += bf2f_lo(u.y) * wk[k].z;
                acc.w += bf2f_hi(u.y) * wk[k].w;
            }
            uint2 o;
            o.x = pack2bf(acc.x, acc.y);
            o.y = pack2bf(acc.z, acc.w);
            *(uint2*)&buf1[rr][col] = o;
        }
    }
    __syncthreads();

    // ---- Stage C: win GEMM (pipelined weight prefetch) + act -> buf0 ----
    float gvreg[4][4];
#pragma unroll
    for (int nn = 0; nn < 4; ++nn) {
        shortx8 Bn[8];
        if (nn < 3) {
            const unsigned short* wp = ww + (size_t)((w + (nn + 1) * 8) * 16 + c16) * 256 + q * 8;
#pragma unroll
            for (int kk = 0; kk < 8; ++kk) Bn[kk] = *(const shortx8*)(wp + kk * 32);
        } else {
            const unsigned short* wp = ow + (size_t)(w * 16 + c16) * 256 + q * 8;  // wout tile 0
#pragma unroll
            for (int kk = 0; kk < 8; ++kk) Bn[kk] = *(const shortx8*)(wp + kk * 32);
        }
        floatx4 acc = {};
#pragma unroll
        for (int kk = 0; kk < 8; ++kk) {
            shortx8 a = *(const shortx8*)&buf1[c16][kk * 32 + q * 8];
            acc = __builtin_amdgcn_mfma_f32_16x16x32_bf16(a, Bf[kk], acc, 0, 0, 0);
        }
        float bb = wb[(w + nn * 8) * 16 + c16];
#pragma unroll
        for (int r = 0; r < 4; ++r) gvreg[nn][r] = acc[r] + bb;
#pragma unroll
        for (int kk = 0; kk < 8; ++kk) Bf[kk] = Bn[kk];
    }
    // act: sigmoid(gate) * gelu_tanh(val) -> buf0 rows 0..15
#pragma unroll
    for (int pp = 0; pp < 2; ++pp) {
        int colw = (w + pp * 8) * 16 + c16;
#pragma unroll
        for (int r = 0; r < 4; ++r) {
            float gate = gvreg[pp][r];
            float val  = gvreg[pp + 2][r];
            float sg = 1.0f / (1.0f + __expf(-gate));
            float u = 1.5957691216f * (val + 0.044715f * val * val * val);
            float ge = val / (1.0f + __expf(-u));
            buf0[q * 4 + r][colw] = f2bf(sg * ge);
        }
    }
    __syncthreads();

    // ---- Stage D: wout GEMM + residual ----
    float vreg[2][4];
#pragma unroll
    for (int nn = 0; nn < 2; ++nn) {
        int nt = w + nn * 8;
        shortx8 Bn[8];
        if (nn == 0) {
            const unsigned short* wp = ow + (size_t)((w + 8) * 16 + c16) * 256 + q * 8;
#pragma unroll
            for (int kk = 0; kk < 8; ++kk) Bn[kk] = *(const shortx8*)(wp + kk * 32);
        }
        float res[4];
#pragma unroll
        for (int r = 0; r < 4; ++r)
            res[r] = hin[((size_t)b * T_ + t0 + q * 4 + r) * D_ + nt * 16 + c16];
        floatx4 acc = {};
#pragma unroll
        for (int kk = 0; kk < 8; ++kk) {
            shortx8 a = *(const shortx8*)&buf0[c16][kk * 32 + q * 8];
            acc = __builtin_amdgcn_mfma_f32_16x16x32_bf16(a, Bf[kk], acc, 0, 0, 0);
        }
        float bb = ob[nt * 16 + c16];
#pragma unroll
        for (int r = 0; r < 4; ++r) vreg[nn][r] = res[r] + acc[r] + bb;
        if (nn == 0) {
#pragma unroll
            for (int kk = 0; kk < 8; ++kk) Bf[kk] = Bn[kk];
        }
    }

    if (!last) {
#pragma unroll
        for (int nn = 0; nn < 2; ++nn)
#pragma unroll
            for (int r = 0; r < 4; ++r)
                hout[((size_t)b * T_ + t0 + q * 4 + r) * D_ + (w + nn * 8) * 16 + c16] = vreg[nn][r];
    } else {
        // final LN over register-resident h' (cross-wave stats)
#pragma unroll
        for (int r = 0; r < 4; ++r) {
            float s = vreg[0][r] + vreg[1][r];
            float ss = vreg[0][r] * vreg[0][r] + vreg[1][r] * vreg[1][r];
#pragma unroll
            for (int off = 1; off < 16; off <<= 1) {
                s += __shfl_xor(s, off);
                ss += __shfl_xor(ss, off);
            }
            if (c16 == 0) {
                rowS[w][q * 4 + r] = s;
                rowSS[w][q * 4 + r] = ss;
            }
        }
        __syncthreads();
        if (tid < ORS_) {
            float s = 0.f, ss = 0.f;
#pragma unroll
            for (int i = 0; i < 8; ++i) { s += rowS[i][tid]; ss += rowSS[i][tid]; }
            float mu = s * (1.0f / D_);
            float var = ss * (1.0f / D_) - mu * mu;
            st[tid] = make_float2(mu, rsqrtf(var + EPS_));
        }
        __syncthreads();
#pragma unroll
        for (int nn = 0; nn < 2; ++nn) {
            int col = (w + nn * 8) * 16 + c16;
            float gg = fn_g[col], bb = fn_b[col];
#pragma unroll
            for (int r = 0; r < 4; ++r) {
                int row = q * 4 + r;
                float2 sv = st[row];
                out0[((size_t)b * T_ + t0 + row) * D_ + col] =
                    (vreg[nn][r] - sv.x) * sv.y * gg + bb;
            }
        }
        if (tid < ORS_) out1[(size_t)b * T_ + t0 + tid] = 1.0f;
    }
}

// ---------------------------------------------------------------------------
extern "C" void kernel_launch(void* const* d_in, const int* in_sizes, int n_in,
                              void* d_out, int out_size, void* d_ws, size_t ws_size,
                              hipStream_t stream) {
    const float* x      = (const float*)d_in[0];
    const unsigned int* mask_w = (const unsigned int*)d_in[1];
    const float* in_w   = (const float*)d_in[2];
    const float* in_b   = (const float*)d_in[3];
    const float* ln_g   = (const float*)d_in[4];
    const float* ln_b   = (const float*)d_in[5];
    const float* dw_w   = (const float*)d_in[6];
    const float* dw_b   = (const float*)d_in[7];
    const float* win_w  = (const float*)d_in[8];
    const float* win_b  = (const float*)d_in[9];
    const float* wout_w = (const float*)d_in[10];
    const float* wout_b = (const float*)d_in[11];
    const float* fn_g   = (const float*)d_in[12];
    const float* fn_b   = (const float*)d_in[13];

    char* w8 = (char*)d_ws;
    unsigned short* wt_in   = (unsigned short*)w8;                 // 128 KB
    unsigned short* wt_win  = wt_in  + (size_t)D_ * DIN_;          // 1 MB
    unsigned short* wt_wout = wt_win + (size_t)NB_ * 2 * D_ * D_;  // 512 KB
    int* lengths = (int*)(w8 + (2u << 20));
    float* h0 = (float*)(w8 + (4u << 20));    // 8 MB
    float* h1 = (float*)(w8 + (12u << 20));   // 8 MB

    float* out0 = (float*)d_out;
    float* out1 = out0 + (size_t)ROWS_ * D_;

    k_setup<<<dim3(16, 8, 10), 256, 0, stream>>>(in_w, win_w, wout_w, mask_w,
                                                 wt_in, wt_win, wt_wout, lengths);
    k_front<<<512, 512, 0, stream>>>(x, lengths, wt_in, in_b, h0);

    for (int li = 0; li < NB_; ++li) {
        const float* hin = (li & 1) ? h1 : h0;
        float* hout      = (li & 1) ? h0 : h1;
        k_blk<<<512, 512, 0, stream>>>(
            hin, hout,
            ln_g + li * D_, ln_b + li * D_,
            dw_w + li * D_ * K_, dw_b + li * D_,
            wt_win + (size_t)li * 2 * D_ * D_, win_b + li * 2 * D_,
            wt_wout + (size_t)li * D_ * D_, wout_b + li * D_,
            fn_g, fn_b, out0, out1, li == 3 ? 1 : 0);
    }
}